// Round 8
// baseline (117.375 us; speedup 1.0000x reference)
//
#include <hip/hip_runtime.h>

typedef short    bf16x8 __attribute__((ext_vector_type(8)));
typedef float    f32x4  __attribute__((ext_vector_type(4)));
typedef unsigned u32x4  __attribute__((ext_vector_type(4)));

#define L_RES 1280
#define A_ATM 14
#define K_NB  30
#define FEAT  656
#define NKB   21            // K-blocks of 32 (672 padded)
#define NCH   128
#define SLAB_K 40           // ushorts per slab row: 32 k + 8 pad; 80 B, 16-B aligned
#define E_OUT_OFF (L_RES * K_NB * NCH)

// fp32 -> bf16 RNE (for W)
__device__ __forceinline__ ushort f2bf(float x) {
    union { float f; unsigned u; } v; v.f = x;
    return (ushort)((v.u + 0x7fffu + ((v.u >> 16) & 1u)) >> 16);
}
__device__ __forceinline__ unsigned pk2rne(float lo, float hi) {
    return (unsigned)f2bf(lo) | ((unsigned)f2bf(hi) << 16);
}
// truncating pack for A features (cheap; validated R7)
__device__ __forceinline__ unsigned pkbf(float lo, float hi) {
    union { float f; unsigned u; } a, b; a.f = lo; b.f = hi;
    return (a.u >> 16) | (b.u & 0xffff0000u);
}

// Single kernel. Block = 2 residues, 4 waves; wave (rh, mt) owns the 16-edge
// m-tile mt of residue blk*2+rh, full K. W is staged per-kb into a
// double-buffered LDS slab (fp32 coalesced read -> bf16 transposed write),
// shared by all 4 waves. One barrier per kb.
__global__ __launch_bounds__(256) void sidechain_one_kernel(
    const float* __restrict__ X,
    const int*   __restrict__ ridx,
    const int*   __restrict__ clab,
    const int*   __restrict__ Eidx,
    const float* __restrict__ Wpos,
    const float* __restrict__ bpos,
    const float* __restrict__ Wedge,
    const float* __restrict__ gamma,
    const float* __restrict__ beta,
    float* __restrict__ out)
{
    __shared__ ushort slab[2][NCH][SLAB_K];              // 20,480 B: slab[p][c][k]
    __shared__ __align__(16) float scj[2][K_NB][10][4];  // 9,600 B
    __shared__ float bbs[2][4][3];

    const int blk  = blockIdx.x;       // residues 2*blk, 2*blk+1
    const int t    = threadIdx.x;
    const int w    = t >> 6;
    const int lane = t & 63;
    const int rh   = w & 1;            // residue within block
    const int mt   = w >> 1;           // m-tile (edges mt*16 .. mt*16+15)
    const int i    = blk * 2 + rh;
    const int frow = lane & 15;
    const int quad = lane >> 4;

    // ---- W slab staging: tasks g = s*256+t; kp = g&15 (k-pair), cq = g>>4 ----
    // writes slab[p][c][k] = bf16(W[kb*32+k][c]); 2-way LDS write conflicts only.
    auto stage_slab = [&](int kb, int p) {
        unsigned* base = (unsigned*)&slab[p][0][0];
#pragma unroll
        for (int s = 0; s < 2; s++) {
            int g  = s * 256 + t;
            int kp = g & 15, cq = g >> 4;          // cq 0..31
            int k  = kb * 32 + 2 * kp;
            if (k + 1 < FEAT) {
                const float* src = Wedge + (size_t)k * NCH + cq * 4;
                float4 r0 = *(const float4*)src;
                float4 r1 = *(const float4*)(src + NCH);
                base[(4 * cq + 0) * (SLAB_K / 2) + kp] = pk2rne(r0.x, r1.x);
                base[(4 * cq + 1) * (SLAB_K / 2) + kp] = pk2rne(r0.y, r1.y);
                base[(4 * cq + 2) * (SLAB_K / 2) + kp] = pk2rne(r0.z, r1.z);
                base[(4 * cq + 3) * (SLAB_K / 2) + kp] = pk2rne(r0.w, r1.w);
            } else {
                base[(4 * cq + 0) * (SLAB_K / 2) + kp] = 0u;
                base[(4 * cq + 1) * (SLAB_K / 2) + kp] = 0u;
                base[(4 * cq + 2) * (SLAB_K / 2) + kp] = 0u;
                base[(4 * cq + 3) * (SLAB_K / 2) + kp] = 0u;
            }
        }
    };

    // ---- coordinate staging + E_idx passthrough ----
    if (t < 24) {
        const int perm[4] = {1, 0, 2, 3};
        int r = t / 12, rr = t - r * 12, a = rr / 3, c = rr - a * 3;
        bbs[r][a][c] = X[((blk * 2 + r) * A_ATM + perm[a]) * 3 + c];
    }
    if (t < 2 * K_NB) {
        int gid = blk * 2 * K_NB + t;
        out[E_OUT_OFF + gid] = (float)Eidx[gid];
    }
    for (int idx = t; idx < 600; idx += 256) {           // 2 res x 30 edges x 10 atoms
        int r = idx / 300, rem = idx - r * 300;
        int e = rem / 10, a = rem - e * 10;
        int j = Eidx[(blk * 2 + r) * K_NB + e];
        const float* xp = X + ((size_t)j * A_ATM + 4 + a) * 3;
        *(float4*)&scj[r][e][a][0] = make_float4(xp[0], xp[1], xp[2], 0.f);
    }
    stage_slab(0, 0);

    // ---- per-lane A-row metadata: this lane generates A[row eA][k-chunk] ----
    const int  eA = mt * 16 + frow;
    const bool vA = (eA < K_NB);                 // rows 30,31 are zero padding
    const int  jA = vA ? Eidx[i * K_NB + eA] : 0;
    const bool okA = vA && (jA != i);            // AUTOREGRESSIVE self-edge mask
    int dA = 65;
    if (vA && clab[i] == clab[jA]) {
        int o = ridx[i] - ridx[jA] + 32;
        dA = o < 0 ? 0 : (o > 64 ? 64 : o);
    }

    const float cs     = 0.96089795f;            // 0.8 * sqrt(log2 e)
    const float mustep = 1.33333333f * cs;
    const int   r0     = (quad & 1) * 8;
    const float mubase = (2.0f + (float)r0 * 1.33333333f) * cs;

    f32x4 acc[8];
#pragma unroll
    for (int n = 0; n < 8; n++) acc[n] = (f32x4){0.f, 0.f, 0.f, 0.f};

    __syncthreads();

    // ---- main K-loop: stage kb+1, compute kb, barrier ----
    for (int kb = 0; kb < NKB; kb++) {
        if (kb + 1 < NKB) stage_slab(kb + 1, (kb + 1) & 1);

        // B fragments from current slab (conflict-free ds_read_b128)
        const int p = kb & 1;
        bf16x8 bfr[8];
#pragma unroll
        for (int n = 0; n < 8; n++)
            bfr[n] = *(const bf16x8*)&slab[p][n * 16 + frow][quad * 8];

        // A fragment generated inline
        union { u32x4 u; bf16x8 h; } A;
        if (kb == 0 && quad < 2) {
            // positional chunk: cols c = quad*8 + j
            float pv[8];
#pragma unroll
            for (int j = 0; j < 8; j++) {
                int c = quad * 8 + j;
                pv[j] = vA ? (Wpos[dA * 16 + c] + bpos[c]) : 0.f;
            }
#pragma unroll
            for (int jj = 0; jj < 4; jj++)
                A.u[jj] = pkbf(pv[2 * jj], pv[2 * jj + 1]);
        } else {
            // RBF half-pair: p = 2kb-1+(quad>>1), rbf r0..r0+7
            int  pr = 2 * kb - 1 + (quad >> 1);
            bool kv = (pr < 40);                 // k >= 656 -> zero pad
            int  pp = kv ? pr : 0;
            int  ab = pp / 10, as = pp - ab * 10;
            float bx = bbs[rh][ab][0], by = bbs[rh][ab][1], bz = bbs[rh][ab][2];
            f32x4 sc = *(const f32x4*)&scj[rh][vA ? eA : 0][as][0];
            float dx = bx - sc[0], dy = by - sc[1], dz = bz - sc[2];
            float dd = sqrtf(dx * dx + dy * dy + dz * dz + 1e-6f) * cs - mubase;
            bool m = kv && okA;
#pragma unroll
            for (int jj = 0; jj < 4; jj++) {
                float cA = (float)(2 * jj) * mustep;
                float cB = (float)(2 * jj + 1) * mustep;
                float tA = dd - cA, tB = dd - cB;
                unsigned q = pkbf(exp2f(-(tA * tA)), exp2f(-(tB * tB)));
                A.u[jj] = m ? q : 0u;
            }
        }

#pragma unroll
        for (int n = 0; n < 8; n++)
            acc[n] = __builtin_amdgcn_mfma_f32_16x16x32_bf16(A.h, bfr[n], acc[n], 0, 0, 0);

        __syncthreads();
    }

    // ---- in-register LayerNorm + store ----
    // C/D layout (m89/m91): col = frow (ch within n-tile), row = quad*4 + r
    float g[8], bt[8];
#pragma unroll
    for (int n = 0; n < 8; n++) {
        g[n]  = gamma[n * 16 + frow];
        bt[n] = beta[n * 16 + frow];
    }
#pragma unroll
    for (int r = 0; r < 4; r++) {
        float s = 0.f, q = 0.f;
#pragma unroll
        for (int n = 0; n < 8; n++) {
            float v = acc[n][r];
            s += v; q += v * v;
        }
#pragma unroll
        for (int off = 1; off < 16; off <<= 1) {
            s += __shfl_xor(s, off);
            q += __shfl_xor(q, off);
        }
        float mean = s * (1.0f / 128.0f);
        float var  = q * (1.0f / 128.0f) - mean * mean;
        float rstd = rsqrtf(var + 1e-5f);
        int edge = mt * 16 + quad * 4 + r;
        if (edge < K_NB) {
            float* o = out + ((size_t)i * K_NB + edge) * NCH + frow;
#pragma unroll
            for (int n = 0; n < 8; n++)
                o[n * 16] = (acc[n][r] - mean) * rstd * g[n] + bt[n];
        }
    }
}

extern "C" void kernel_launch(void* const* d_in, const int* in_sizes, int n_in,
                              void* d_out, int out_size, void* d_ws, size_t ws_size,
                              hipStream_t stream) {
    const float* X     = (const float*)d_in[0];
    const int*   ridx  = (const int*)  d_in[1];
    const int*   clab  = (const int*)  d_in[2];
    const int*   Eidx  = (const int*)  d_in[3];
    // d_in[4] = atom_mask (unused by reference forward)
    const float* Wpos  = (const float*)d_in[5];
    const float* bpos  = (const float*)d_in[6];
    const float* Wedge = (const float*)d_in[7];
    const float* gamma = (const float*)d_in[8];
    const float* beta  = (const float*)d_in[9];
    float* out = (float*)d_out;

    sidechain_one_kernel<<<L_RES / 2, 256, 0, stream>>>(
        X, ridx, clab, Eidx, Wpos, bpos, Wedge, gamma, beta, out);
}